// Round 1
// baseline (300.968 us; speedup 1.0000x reference)
//
#include <hip/hip_runtime.h>
#include <hip/hip_bf16.h>
#include <math.h>

#define BATCHES 8
#define SEQ 1024
#define DDIM 768
#define BM 128
#define BN 128
#define BK 16
#define PAD 17   // LDS leading-dim pad: conflict-free broadcast reads

// ---------------- Kernel 1: projections + const + zero sums ----------------
__global__ __launch_bounds__(256) void proj_kernel(
    const float* __restrict__ S, const float* __restrict__ T,
    const float* __restrict__ W, const float* __restrict__ bcost,
    const float* __restrict__ temb, const int* __restrict__ task_id,
    float* __restrict__ sproj, float* __restrict__ tproj,
    float* __restrict__ cterm, double* __restrict__ batch_sums)
{
    // zero the 16 doubles of batch accumulators (block 0)
    if (blockIdx.x == 0 && threadIdx.x < 16) batch_sums[threadIdx.x] = 0.0;

    int gw   = (blockIdx.x * blockDim.x + threadIdx.x) >> 6; // global wave id
    int lane = threadIdx.x & 63;

    if (gw < 2 * BATCHES * SEQ) {
        const float* rowp = (gw < BATCHES * SEQ)
            ? S + (size_t)gw * DDIM
            : T + (size_t)(gw - BATCHES * SEQ) * DDIM;
        float s = 0.f;
        #pragma unroll
        for (int d = lane; d < DDIM; d += 64) s = fmaf(rowp[d], W[d], s);
        #pragma unroll
        for (int o = 32; o; o >>= 1) s += __shfl_down(s, o);
        if (lane == 0) {
            if (gw < BATCHES * SEQ) sproj[gw] = s;
            else                    tproj[gw - BATCHES * SEQ] = s;
        }
    }

    // last block, wave 0: task_proj + b_cost
    if (blockIdx.x == gridDim.x - 1 && (threadIdx.x >> 6) == 0) {
        int tid = *task_id;
        float s = 0.f;
        #pragma unroll
        for (int d = lane; d < DDIM; d += 64) s = fmaf(temb[tid * DDIM + d], W[d], s);
        #pragma unroll
        for (int o = 32; o; o >>= 1) s += __shfl_down(s, o);
        if (lane == 0) *cterm = s + bcost[0];
    }
}

// ------------- Kernel 2: batched NT GEMM + (1-cos)/2 + sum/sumsq -------------
__global__ __launch_bounds__(256) void gemm_cos_kernel(
    const float* __restrict__ S, const float* __restrict__ T,
    float* __restrict__ out, double* __restrict__ batch_sums)
{
    __shared__ float As[BM][PAD];
    __shared__ float Bs[BN][PAD];

    const int t  = threadIdx.x;
    const int tx = t & 15;
    const int ty = t >> 4;
    const int batch = blockIdx.z;
    const int row0 = blockIdx.y * BM;
    const int col0 = blockIdx.x * BN;

    const float* Sb = S + (size_t)batch * SEQ * DDIM;
    const float* Tb = T + (size_t)batch * SEQ * DDIM;

    // staging map: 4 threads per row, each thread rows lr and lr+64, 4 floats each
    const int lr = t >> 2;          // 0..63
    const int kc = (t & 3) * 4;     // 0,4,8,12

    float4 sA0, sA1, sB0, sB1;

    const float* pA0 = &Sb[(size_t)(row0 + lr) * DDIM + kc];
    const float* pA1 = &Sb[(size_t)(row0 + lr + 64) * DDIM + kc];
    const float* pB0 = &Tb[(size_t)(col0 + lr) * DDIM + kc];
    const float* pB1 = &Tb[(size_t)(col0 + lr + 64) * DDIM + kc];

    float acc[8][8] = {};

    // prefetch k0 = 0
    sA0 = *(const float4*)(pA0);
    sA1 = *(const float4*)(pA1);
    sB0 = *(const float4*)(pB0);
    sB1 = *(const float4*)(pB1);

    #pragma unroll 1
    for (int k0 = 0; k0 < DDIM; k0 += BK) {
        // store staged regs -> LDS
        As[lr][kc + 0] = sA0.x; As[lr][kc + 1] = sA0.y; As[lr][kc + 2] = sA0.z; As[lr][kc + 3] = sA0.w;
        As[lr + 64][kc + 0] = sA1.x; As[lr + 64][kc + 1] = sA1.y; As[lr + 64][kc + 2] = sA1.z; As[lr + 64][kc + 3] = sA1.w;
        Bs[lr][kc + 0] = sB0.x; Bs[lr][kc + 1] = sB0.y; Bs[lr][kc + 2] = sB0.z; Bs[lr][kc + 3] = sB0.w;
        Bs[lr + 64][kc + 0] = sB1.x; Bs[lr + 64][kc + 1] = sB1.y; Bs[lr + 64][kc + 2] = sB1.z; Bs[lr + 64][kc + 3] = sB1.w;
        __syncthreads();

        // prefetch next tile while computing this one
        if (k0 + BK < DDIM) {
            int kn = k0 + BK;
            sA0 = *(const float4*)(pA0 + kn);
            sA1 = *(const float4*)(pA1 + kn);
            sB0 = *(const float4*)(pB0 + kn);
            sB1 = *(const float4*)(pB1 + kn);
        }

        #pragma unroll
        for (int kk = 0; kk < BK; ++kk) {
            float a[8], b[8];
            #pragma unroll
            for (int m = 0; m < 8; ++m) a[m] = As[ty + 16 * m][kk];
            #pragma unroll
            for (int n = 0; n < 8; ++n) b[n] = Bs[tx + 16 * n][kk];
            #pragma unroll
            for (int m = 0; m < 8; ++m)
                #pragma unroll
                for (int n = 0; n < 8; ++n)
                    acc[m][n] = fmaf(a[m], b[n], acc[m][n]);
        }
        __syncthreads();
    }

    // epilogue: c0 = (1 - cos(dot))/2, store, accumulate sum/sumsq
    float lsum = 0.f, lsq = 0.f;
    float* outb = out + (size_t)batch * SEQ * SEQ;
    #pragma unroll
    for (int m = 0; m < 8; ++m) {
        int r = row0 + ty + 16 * m;
        #pragma unroll
        for (int n = 0; n < 8; ++n) {
            int c = col0 + tx + 16 * n;
            float d  = acc[m][n];
            float c0 = 0.5f - 0.5f * __cosf(d);
            outb[(size_t)r * SEQ + c] = c0;
            lsum += c0;
            lsq  = fmaf(c0, c0, lsq);
        }
    }

    // block reduction (double) -> atomics
    double s = (double)lsum, q = (double)lsq;
    #pragma unroll
    for (int o = 32; o; o >>= 1) { s += __shfl_down(s, o); q += __shfl_down(q, o); }
    __shared__ double red[8];
    int w = t >> 6, lane = t & 63;
    if (lane == 0) { red[w] = s; red[4 + w] = q; }
    __syncthreads();
    if (t == 0) {
        s = red[0] + red[1] + red[2] + red[3];
        q = red[4] + red[5] + red[6] + red[7];
        atomicAdd(&batch_sums[batch * 2 + 0], s);
        atomicAdd(&batch_sums[batch * 2 + 1], q);
    }
}

// ---------------- Kernel 3: finalize ----------------
__global__ __launch_bounds__(256) void finalize_kernel(
    float* __restrict__ out, const double* __restrict__ batch_sums,
    const float* __restrict__ sproj, const float* __restrict__ tproj,
    const float* __restrict__ cterm_p, const float* __restrict__ alpha_p)
{
    const double n = (double)SEQ * (double)SEQ;
    size_t idx4 = (size_t)blockIdx.x * blockDim.x + threadIdx.x;
    size_t base = idx4 * 4;
    int batch = (int)(base >> 20);
    int rem   = (int)(base & ((SEQ * SEQ) - 1));
    int srow  = rem >> 10;
    int tcol  = rem & (SEQ - 1);

    double sum = batch_sums[batch * 2 + 0];
    double sq  = batch_sums[batch * 2 + 1];
    double var = (sq - sum * sum / n) / (n - 1.0);
    float inv_std = (float)(1.0 / sqrt(var));

    float alpha = *alpha_p;
    float ct    = *cterm_p;
    float sp    = sproj[batch * SEQ + srow];
    float4 tp   = *(const float4*)&tproj[batch * SEQ + tcol];
    float4 c    = *(float4*)&out[base];

    float4 r;
    {
        float x = c.x * inv_std; float g = __expf(-0.5f * x * x);
        float z = sp + tp.x + ct; float cd = 1.f / (1.f + __expf(-z));
        r.x = alpha * (g + cd);
    }
    {
        float x = c.y * inv_std; float g = __expf(-0.5f * x * x);
        float z = sp + tp.y + ct; float cd = 1.f / (1.f + __expf(-z));
        r.y = alpha * (g + cd);
    }
    {
        float x = c.z * inv_std; float g = __expf(-0.5f * x * x);
        float z = sp + tp.z + ct; float cd = 1.f / (1.f + __expf(-z));
        r.z = alpha * (g + cd);
    }
    {
        float x = c.w * inv_std; float g = __expf(-0.5f * x * x);
        float z = sp + tp.w + ct; float cd = 1.f / (1.f + __expf(-z));
        r.w = alpha * (g + cd);
    }
    *(float4*)&out[base] = r;
}

// ---------------- launch ----------------
extern "C" void kernel_launch(void* const* d_in, const int* in_sizes, int n_in,
                              void* d_out, int out_size, void* d_ws, size_t ws_size,
                              hipStream_t stream) {
    const float* S      = (const float*)d_in[0];
    const float* T      = (const float*)d_in[1];
    const float* W      = (const float*)d_in[2];
    const float* bcost  = (const float*)d_in[3];
    const float* temb   = (const float*)d_in[4];
    const float* alpha  = (const float*)d_in[5];
    const int*   taskid = (const int*)d_in[6];
    float* out = (float*)d_out;

    double* batch_sums = (double*)d_ws;                       // 16 doubles
    float*  sproj = (float*)((char*)d_ws + 128);              // 8192 floats
    float*  tproj = sproj + BATCHES * SEQ;                    // 8192 floats
    float*  cterm = tproj + BATCHES * SEQ;                    // 1 float

    // 1) projections: 16384 rows, 1 wave each, 4 waves/block -> 4096 (+1) blocks
    proj_kernel<<<4097, 256, 0, stream>>>(S, T, W, bcost, temb, taskid,
                                          sproj, tproj, cterm, batch_sums);

    // 2) batched GEMM + cos + reduce
    dim3 grid(SEQ / BN, SEQ / BM, BATCHES);
    gemm_cos_kernel<<<grid, 256, 0, stream>>>(S, T, out, batch_sums);

    // 3) finalize
    int nblk = (BATCHES * SEQ * SEQ) / (256 * 4);
    finalize_kernel<<<nblk, 256, 0, stream>>>(out, batch_sums, sproj, tproj,
                                              cterm, alpha);
}

// Round 2
// 93.055 us; speedup vs baseline: 3.2343x; 3.2343x over previous
//
#include <hip/hip_runtime.h>
#include <hip/hip_bf16.h>
#include <math.h>

#define BATCHES 8
#define SEQ 1024
#define DDIM 768
#define NPANEL 8          // 1024 / 128 row-panels
#define NKSTEP 24         // 768 / 32 k-steps
#define CHUNK_U 8192      // ushorts per (panel,kstep) chunk: hi 4096 + lo 4096

typedef unsigned short u16;
typedef __attribute__((ext_vector_type(8))) short bf16x8;
typedef __attribute__((ext_vector_type(8))) unsigned short u16x8;
typedef __attribute__((ext_vector_type(4))) float f32x4;

static __device__ __forceinline__ u16 f2bf(float x) {
    union { float f; unsigned u; } v; v.f = x;
    unsigned r = v.u + 0x7FFFu + ((v.u >> 16) & 1u);   // RNE
    return (u16)(r >> 16);
}
static __device__ __forceinline__ float bf2f(u16 h) {
    union { float f; unsigned u; } v; v.u = ((unsigned)h) << 16; return v.f;
}

__device__ __forceinline__ void glds16(const u16* g, u16* l) {
    __builtin_amdgcn_global_load_lds(
        (const __attribute__((address_space(1))) void*)g,
        (__attribute__((address_space(3))) void*)l, 16, 0, 0);
}

// ---------------- Kernel 1: projections + const + zero sums ----------------
__global__ __launch_bounds__(256) void proj_kernel(
    const float* __restrict__ S, const float* __restrict__ T,
    const float* __restrict__ W, const float* __restrict__ bcost,
    const float* __restrict__ temb, const int* __restrict__ task_id,
    float* __restrict__ sproj, float* __restrict__ tproj,
    float* __restrict__ cterm, double* __restrict__ batch_sums)
{
    if (blockIdx.x == 0 && threadIdx.x < 16) batch_sums[threadIdx.x] = 0.0;

    int gw   = (blockIdx.x * blockDim.x + threadIdx.x) >> 6;
    int lane = threadIdx.x & 63;

    if (gw < 2 * BATCHES * SEQ) {
        const float* rowp = (gw < BATCHES * SEQ)
            ? S + (size_t)gw * DDIM
            : T + (size_t)(gw - BATCHES * SEQ) * DDIM;
        float s = 0.f;
        #pragma unroll
        for (int d = lane; d < DDIM; d += 64) s = fmaf(rowp[d], W[d], s);
        #pragma unroll
        for (int o = 32; o; o >>= 1) s += __shfl_down(s, o);
        if (lane == 0) {
            if (gw < BATCHES * SEQ) sproj[gw] = s;
            else                    tproj[gw - BATCHES * SEQ] = s;
        }
    }

    if (blockIdx.x == gridDim.x - 1 && (threadIdx.x >> 6) == 0) {
        int tid = *task_id;
        float s = 0.f;
        #pragma unroll
        for (int d = lane; d < DDIM; d += 64) s = fmaf(temb[tid * DDIM + d], W[d], s);
        #pragma unroll
        for (int o = 32; o; o >>= 1) s += __shfl_down(s, o);
        if (lane == 0) *cterm = s + bcost[0];
    }
}

// ------- Kernel 2: fp32 -> bf16 hi/lo, pre-tiled in MFMA fragment order -------
// chunk(b,p,ks) = [hi: m(8) kg(4) r(16) e(8)][lo: same]  (16 KB, glds-linear)
__global__ __launch_bounds__(256) void convert_kernel(
    const float* __restrict__ S, const float* __restrict__ T,
    u16* __restrict__ Sg, u16* __restrict__ Tg)
{
    int cid = blockIdx.x;
    int ks = cid % NKSTEP; int rest = cid / NKSTEP;
    int p = rest & 7; rest >>= 3;
    int b = rest & 7; int tensor = rest >> 3;

    const float* src = (tensor ? T : S) + (size_t)b * SEQ * DDIM;
    u16* dst = (tensor ? Tg : Sg) + (size_t)((b * NPANEL + p) * NKSTEP + ks) * CHUNK_U;

    int t = threadIdx.x;
    #pragma unroll
    for (int i = 0; i < 2; ++i) {
        int g = t + i * 256;                 // 0..511
        int m = g >> 6, kg = (g >> 4) & 3, r = g & 15;
        const float* sp = src + (size_t)(p * 128 + m * 16 + r) * DDIM + ks * 32 + kg * 8;
        float4 f0 = *(const float4*)sp;
        float4 f1 = *(const float4*)(sp + 4);
        float xs[8] = {f0.x, f0.y, f0.z, f0.w, f1.x, f1.y, f1.z, f1.w};
        u16x8 vh, vl;
        #pragma unroll
        for (int e = 0; e < 8; ++e) {
            u16 h = f2bf(xs[e]);
            float rem = xs[e] - bf2f(h);
            vh[e] = h;
            vl[e] = f2bf(rem);
        }
        *(u16x8*)(dst + (size_t)g * 8)        = vh;
        *(u16x8*)(dst + 4096 + (size_t)g * 8) = vl;
    }
}

// ------------- Kernel 3: MFMA GEMM (bf16 split) + cos + sum/sumsq -------------
template <bool FUSED>
__global__ __launch_bounds__(256) void gemm_kernel(
    const float* __restrict__ S, const float* __restrict__ T,
    const u16* __restrict__ Sg, const u16* __restrict__ Tg,
    float* __restrict__ out, double* __restrict__ batch_sums)
{
    // per buf: A_hi [0,4096) A_lo [4096,8192) B_hi [8192,12288) B_lo [12288,16384)
    __shared__ __align__(16) u16 lds[2][16384];
    __shared__ double red[8];

    const int t    = threadIdx.x;
    const int lane = t & 63;
    const int w    = t >> 6;
    const int wr   = w >> 1, wc = w & 1;
    const int b = blockIdx.z, by = blockIdx.y, bx = blockIdx.x;

    f32x4 acc[4][4];
    #pragma unroll
    for (int m = 0; m < 4; ++m)
        #pragma unroll
        for (int n = 0; n < 4; ++n) acc[m][n] = (f32x4){0.f, 0.f, 0.f, 0.f};

    // ---- glds path bases ----
    const u16* Achunk = Sg + (size_t)((b * NPANEL + by) * NKSTEP) * CHUNK_U;
    const u16* Bchunk = Tg + (size_t)((b * NPANEL + bx) * NKSTEP) * CHUNK_U;

    // ---- fused path reg staging ----
    const float* Sb = S + (size_t)b * SEQ * DDIM;
    const float* Tb = T + (size_t)b * SEQ * DDIM;
    const float* pa[2]; const float* pb[2];
    float4 ra[2][2], rb[2][2];
    if (FUSED) {
        #pragma unroll
        for (int i = 0; i < 2; ++i) {
            int g = t + i * 256;
            int m = g >> 6, kg = (g >> 4) & 3, r = g & 15;
            pa[i] = Sb + (size_t)(by * 128 + m * 16 + r) * DDIM + kg * 8;
            pb[i] = Tb + (size_t)(bx * 128 + m * 16 + r) * DDIM + kg * 8;
        }
    }

    auto LOADREGS = [&](int ks) {
        #pragma unroll
        for (int i = 0; i < 2; ++i) {
            ra[i][0] = *(const float4*)(pa[i] + ks * 32);
            ra[i][1] = *(const float4*)(pa[i] + ks * 32 + 4);
            rb[i][0] = *(const float4*)(pb[i] + ks * 32);
            rb[i][1] = *(const float4*)(pb[i] + ks * 32 + 4);
        }
    };
    auto STAGE_FUSED = [&](int buf) {
        #pragma unroll
        for (int i = 0; i < 2; ++i) {
            int g = t + i * 256;
            float xa[8] = {ra[i][0].x, ra[i][0].y, ra[i][0].z, ra[i][0].w,
                           ra[i][1].x, ra[i][1].y, ra[i][1].z, ra[i][1].w};
            float xb[8] = {rb[i][0].x, rb[i][0].y, rb[i][0].z, rb[i][0].w,
                           rb[i][1].x, rb[i][1].y, rb[i][1].z, rb[i][1].w};
            u16x8 ah, al, bh, bl;
            #pragma unroll
            for (int e = 0; e < 8; ++e) {
                u16 h = f2bf(xa[e]); ah[e] = h; al[e] = f2bf(xa[e] - bf2f(h));
                u16 g2 = f2bf(xb[e]); bh[e] = g2; bl[e] = f2bf(xb[e] - bf2f(g2));
            }
            *(u16x8*)&lds[buf][(size_t)g * 8]         = ah;
            *(u16x8*)&lds[buf][4096 + (size_t)g * 8]  = al;
            *(u16x8*)&lds[buf][8192 + (size_t)g * 8]  = bh;
            *(u16x8*)&lds[buf][12288 + (size_t)g * 8] = bl;
        }
    };
    auto STAGE_GLDS = [&](int ks, int buf) {
        const u16* sa = Achunk + (size_t)ks * CHUNK_U + (w * 4) * 512 + lane * 8;
        const u16* sb = Bchunk + (size_t)ks * CHUNK_U + (w * 4) * 512 + lane * 8;
        #pragma unroll
        for (int j = 0; j < 4; ++j)
            glds16(sa + j * 512, &lds[buf][(w * 4 + j) * 512]);
        #pragma unroll
        for (int j = 0; j < 4; ++j)
            glds16(sb + j * 512, &lds[buf][8192 + (w * 4 + j) * 512]);
    };
    auto COMPUTE = [&](int buf) {
        const u16* L = &lds[buf][0];
        bf16x8 ah[4], al[4], bh[4], bl[4];
        #pragma unroll
        for (int m = 0; m < 4; ++m) {
            int sm = wr * 4 + m;
            ah[m] = *(const bf16x8*)(L + sm * 512 + lane * 8);
            al[m] = *(const bf16x8*)(L + 4096 + sm * 512 + lane * 8);
        }
        #pragma unroll
        for (int n = 0; n < 4; ++n) {
            int sn = wc * 4 + n;
            bh[n] = *(const bf16x8*)(L + 8192 + sn * 512 + lane * 8);
            bl[n] = *(const bf16x8*)(L + 12288 + sn * 512 + lane * 8);
        }
        #pragma unroll
        for (int m = 0; m < 4; ++m)
            #pragma unroll
            for (int n = 0; n < 4; ++n) {
                acc[m][n] = __builtin_amdgcn_mfma_f32_16x16x32_bf16(ah[m], bh[n], acc[m][n], 0, 0, 0);
                acc[m][n] = __builtin_amdgcn_mfma_f32_16x16x32_bf16(ah[m], bl[n], acc[m][n], 0, 0, 0);
                acc[m][n] = __builtin_amdgcn_mfma_f32_16x16x32_bf16(al[m], bh[n], acc[m][n], 0, 0, 0);
            }
    };

    if (FUSED) {
        LOADREGS(0);
        for (int ks = 0; ks < NKSTEP; ++ks) {
            int buf = ks & 1;
            STAGE_FUSED(buf);
            __syncthreads();
            if (ks + 1 < NKSTEP) LOADREGS(ks + 1);
            COMPUTE(buf);
        }
    } else {
        STAGE_GLDS(0, 0);
        __syncthreads();
        for (int ks = 0; ks < NKSTEP; ++ks) {
            int buf = ks & 1;
            if (ks + 1 < NKSTEP) STAGE_GLDS(ks + 1, buf ^ 1);
            COMPUTE(buf);
            __syncthreads();
        }
    }

    // epilogue: c0 = (1 - cos(dot))/2, store, accumulate sum/sumsq
    float lsum = 0.f, lsq = 0.f;
    float* outb = out + (size_t)b * SEQ * SEQ;
    const int rbase = by * 128 + wr * 64;
    const int cbase = bx * 128 + wc * 64;
    const int cr = lane >> 4;     // C/D: row = cr*4 + j, col = lane & 15
    const int cc = lane & 15;
    #pragma unroll
    for (int m = 0; m < 4; ++m) {
        #pragma unroll
        for (int n = 0; n < 4; ++n) {
            int col = cbase + n * 16 + cc;
            #pragma unroll
            for (int j = 0; j < 4; ++j) {
                int row = rbase + m * 16 + cr * 4 + j;
                float d  = acc[m][n][j];
                float c0 = 0.5f - 0.5f * __cosf(d);
                outb[(size_t)row * SEQ + col] = c0;
                lsum += c0;
                lsq  = fmaf(c0, c0, lsq);
            }
        }
    }

    double s = (double)lsum, q = (double)lsq;
    #pragma unroll
    for (int o = 32; o; o >>= 1) { s += __shfl_down(s, o); q += __shfl_down(q, o); }
    if (lane == 0) { red[w] = s; red[4 + w] = q; }
    __syncthreads();
    if (t == 0) {
        s = red[0] + red[1] + red[2] + red[3];
        q = red[4] + red[5] + red[6] + red[7];
        atomicAdd(&batch_sums[b * 2 + 0], s);
        atomicAdd(&batch_sums[b * 2 + 1], q);
    }
}

// ---------------- Kernel 4: finalize ----------------
__global__ __launch_bounds__(256) void finalize_kernel(
    float* __restrict__ out, const double* __restrict__ batch_sums,
    const float* __restrict__ sproj, const float* __restrict__ tproj,
    const float* __restrict__ cterm_p, const float* __restrict__ alpha_p)
{
    const double n = (double)SEQ * (double)SEQ;
    size_t idx4 = (size_t)blockIdx.x * blockDim.x + threadIdx.x;
    size_t base = idx4 * 4;
    int batch = (int)(base >> 20);
    int rem   = (int)(base & ((SEQ * SEQ) - 1));
    int srow  = rem >> 10;
    int tcol  = rem & (SEQ - 1);

    double sum = batch_sums[batch * 2 + 0];
    double sq  = batch_sums[batch * 2 + 1];
    double var = (sq - sum * sum / n) / (n - 1.0);
    float inv_std = (float)(1.0 / sqrt(var));

    float alpha = *alpha_p;
    float ct    = *cterm_p;
    float sp    = sproj[batch * SEQ + srow];
    float4 tp   = *(const float4*)&tproj[batch * SEQ + tcol];
    float4 c    = *(float4*)&out[base];

    float4 r;
    { float x = c.x * inv_std; float g = __expf(-0.5f * x * x);
      float z = sp + tp.x + ct; float cd = 1.f / (1.f + __expf(-z)); r.x = alpha * (g + cd); }
    { float x = c.y * inv_std; float g = __expf(-0.5f * x * x);
      float z = sp + tp.y + ct; float cd = 1.f / (1.f + __expf(-z)); r.y = alpha * (g + cd); }
    { float x = c.z * inv_std; float g = __expf(-0.5f * x * x);
      float z = sp + tp.z + ct; float cd = 1.f / (1.f + __expf(-z)); r.z = alpha * (g + cd); }
    { float x = c.w * inv_std; float g = __expf(-0.5f * x * x);
      float z = sp + tp.w + ct; float cd = 1.f / (1.f + __expf(-z)); r.w = alpha * (g + cd); }
    *(float4*)&out[base] = r;
}

// ---------------- launch ----------------
extern "C" void kernel_launch(void* const* d_in, const int* in_sizes, int n_in,
                              void* d_out, int out_size, void* d_ws, size_t ws_size,
                              hipStream_t stream) {
    const float* S      = (const float*)d_in[0];
    const float* T      = (const float*)d_in[1];
    const float* W      = (const float*)d_in[2];
    const float* bcost  = (const float*)d_in[3];
    const float* temb   = (const float*)d_in[4];
    const float* alpha  = (const float*)d_in[5];
    const int*   taskid = (const int*)d_in[6];
    float* out = (float*)d_out;

    double* batch_sums = (double*)d_ws;
    float*  sproj = (float*)((char*)d_ws + 128);
    float*  tproj = sproj + BATCHES * SEQ;
    float*  cterm = tproj + BATCHES * SEQ;

    const size_t SMALL = (size_t)1 << 20;
    const size_t CONV_U = (size_t)BATCHES * NPANEL * NKSTEP * CHUNK_U;  // per tensor, ushorts
    const size_t NEEDED = SMALL + 2 * CONV_U * sizeof(u16);
    u16* Sg = (u16*)((char*)d_ws + SMALL);
    u16* Tg = Sg + CONV_U;

    proj_kernel<<<4097, 256, 0, stream>>>(S, T, W, bcost, temb, taskid,
                                          sproj, tproj, cterm, batch_sums);

    dim3 grid(SEQ / 128, SEQ / 128, BATCHES);
    if (ws_size >= NEEDED) {
        convert_kernel<<<2 * BATCHES * NPANEL * NKSTEP, 256, 0, stream>>>(S, T, Sg, Tg);
        gemm_kernel<false><<<grid, 256, 0, stream>>>(S, T, Sg, Tg, out, batch_sums);
    } else {
        gemm_kernel<true><<<grid, 256, 0, stream>>>(S, T, Sg, Tg, out, batch_sums);
    }

    int nblk = (BATCHES * SEQ * SEQ) / (256 * 4);
    finalize_kernel<<<nblk, 256, 0, stream>>>(out, batch_sums, sproj, tproj,
                                              cterm, alpha);
}

// Round 5
// 81.052 us; speedup vs baseline: 3.7133x; 1.1481x over previous
//
#include <hip/hip_runtime.h>
#include <hip/hip_bf16.h>
#include <math.h>

#define BATCHES 8
#define SEQ 1024
#define DDIM 768
#define NPANEL 8          // 1024 / 128 row-panels
#define NKSTEP 24         // 768 / 32 k-steps
#define CHUNK_U 8192      // ushorts per (panel,kstep) chunk: hi 4096 + lo 4096

typedef unsigned short u16;
typedef __attribute__((ext_vector_type(8))) short bf16x8;
typedef __attribute__((ext_vector_type(8))) unsigned short u16x8;
typedef __attribute__((ext_vector_type(4))) float f32x4;

static __device__ __forceinline__ u16 f2bf(float x) {
    union { float f; unsigned u; } v; v.f = x;
    unsigned r = v.u + 0x7FFFu + ((v.u >> 16) & 1u);   // RNE
    return (u16)(r >> 16);
}
static __device__ __forceinline__ float bf2f(u16 h) {
    union { float f; unsigned u; } v; v.u = ((unsigned)h) << 16; return v.f;
}

__device__ __forceinline__ void glds16(const u16* g, u16* l) {
    __builtin_amdgcn_global_load_lds(
        (const __attribute__((address_space(1))) void*)g,
        (__attribute__((address_space(3))) void*)l, 16, 0, 0);
}

// ---- Kernel A: fused convert (fp32 -> hi/lo bf16 pre-tiled) + projections ----
// thread g -> (tensor,b,p,ks,m,kg,r); wave = fixed (m,ks,p,b,tensor), 16 rows x 32 cols
__global__ __launch_bounds__(256) void prep_kernel(
    const float* __restrict__ S, const float* __restrict__ T,
    const float* __restrict__ W, const float* __restrict__ bcost,
    const float* __restrict__ temb, const int* __restrict__ task_id,
    u16* __restrict__ Sg, u16* __restrict__ Tg,
    float* __restrict__ sproj, float* __restrict__ tproj,
    float* __restrict__ cterm)
{
    int t = threadIdx.x;
    int g = blockIdx.x * 256 + t;
    int r  = g & 15;
    int kg = (g >> 4) & 3;
    int m  = (g >> 6) & 7;
    int x  = g >> 9;                 // 0..3071
    int ks = x % NKSTEP; x /= NKSTEP;
    int p  = x & 7;
    int b  = (x >> 3) & 7;
    int tensor = x >> 6;

    int row_loc = p * 128 + m * 16 + r;          // 0..1023
    int row_glb = b * SEQ + row_loc;             // 0..8191
    int col = ks * 32 + kg * 8;

    const float* src = (tensor ? T : S) + (size_t)row_glb * DDIM + col;
    float4 f0 = *(const float4*)src;
    float4 f1 = *(const float4*)(src + 4);
    float4 w0 = *(const float4*)(W + col);
    float4 w1 = *(const float4*)(W + col + 4);

    // projection partial over this thread's 8 elements
    float pd = f0.x * w0.x + f0.y * w0.y + f0.z * w0.z + f0.w * w0.w
             + f1.x * w1.x + f1.y * w1.y + f1.z * w1.z + f1.w * w1.w;
    pd += __shfl_down(pd, 32);
    pd += __shfl_down(pd, 16);
    if ((t & 63) < 16)
        atomicAdd((tensor ? tproj : sproj) + row_glb, pd);

    // convert to hi/lo bf16 and store in chunk layout
    float xs[8] = {f0.x, f0.y, f0.z, f0.w, f1.x, f1.y, f1.z, f1.w};
    u16x8 vh, vl;
    #pragma unroll
    for (int e = 0; e < 8; ++e) {
        u16 h = f2bf(xs[e]);
        vh[e] = h;
        vl[e] = f2bf(xs[e] - bf2f(h));
    }
    u16* dst = (tensor ? Tg : Sg)
             + (size_t)((b * NPANEL + p) * NKSTEP + ks) * CHUNK_U
             + ((m * 4 + kg) * 16 + r) * 8;
    *(u16x8*)dst          = vh;
    *(u16x8*)(dst + 4096) = vl;

    // cterm: block 0, wave 0
    if (blockIdx.x == 0 && t < 64) {
        int tid = *task_id;
        float s = 0.f;
        #pragma unroll
        for (int d = t; d < DDIM; d += 64) s = fmaf(temb[tid * DDIM + d], W[d], s);
        #pragma unroll
        for (int o = 32; o; o >>= 1) s += __shfl_down(s, o);
        if (t == 0) *cterm = s + bcost[0];
    }
}

// -------- fallback proj kernel (small-ws path only) --------
__global__ __launch_bounds__(256) void proj_kernel(
    const float* __restrict__ S, const float* __restrict__ T,
    const float* __restrict__ W, const float* __restrict__ bcost,
    const float* __restrict__ temb, const int* __restrict__ task_id,
    float* __restrict__ sproj, float* __restrict__ tproj,
    float* __restrict__ cterm)
{
    int gw   = (blockIdx.x * blockDim.x + threadIdx.x) >> 6;
    int lane = threadIdx.x & 63;

    if (gw < 2 * BATCHES * SEQ) {
        const float* rowp = (gw < BATCHES * SEQ)
            ? S + (size_t)gw * DDIM
            : T + (size_t)(gw - BATCHES * SEQ) * DDIM;
        float s = 0.f;
        #pragma unroll
        for (int d = lane; d < DDIM; d += 64) s = fmaf(rowp[d], W[d], s);
        #pragma unroll
        for (int o = 32; o; o >>= 1) s += __shfl_down(s, o);
        if (lane == 0) {
            if (gw < BATCHES * SEQ) sproj[gw] = s;
            else                    tproj[gw - BATCHES * SEQ] = s;
        }
    }
    if (blockIdx.x == gridDim.x - 1 && (threadIdx.x >> 6) == 0) {
        int tid = *task_id;
        float s = 0.f;
        #pragma unroll
        for (int d = lane; d < DDIM; d += 64) s = fmaf(temb[tid * DDIM + d], W[d], s);
        #pragma unroll
        for (int o = 32; o; o >>= 1) s += __shfl_down(s, o);
        if (lane == 0) *cterm = s + bcost[0];
    }
}

// ------- Kernel B: MFMA GEMM (bf16 hi/lo) + cos + sum/sumsq, single-buffer -------
template <bool FUSED>
__global__ __launch_bounds__(256) void gemm_kernel(
    const float* __restrict__ S, const float* __restrict__ T,
    const u16* __restrict__ Sg, const u16* __restrict__ Tg,
    float* __restrict__ out, double* __restrict__ batch_sums)
{
    // Ahi [0,4096) Alo [4096,8192) Bhi [8192,12288) Blo [12288,16384)  (u16 idx)
    __shared__ __align__(16) u16 lds[16384];
    __shared__ double red[8];

    const int t    = threadIdx.x;
    const int lane = t & 63;
    const int w    = t >> 6;
    const int wr   = w >> 1, wc = w & 1;

    // XCD-aware swizzle: each XCD gets one batch (512 blocks, 64/XCD)
    int wg = (blockIdx.x & 7) * 64 + (blockIdx.x >> 3);
    const int b  = wg >> 6;
    const int by = (wg >> 3) & 7;
    const int bx = wg & 7;

    f32x4 acc[4][4];
    #pragma unroll
    for (int m = 0; m < 4; ++m)
        #pragma unroll
        for (int n = 0; n < 4; ++n) acc[m][n] = (f32x4){0.f, 0.f, 0.f, 0.f};

    const u16* Achunk = Sg + (size_t)((b * NPANEL + by) * NKSTEP) * CHUNK_U;
    const u16* Bchunk = Tg + (size_t)((b * NPANEL + bx) * NKSTEP) * CHUNK_U;

    const float* Sb = S + (size_t)b * SEQ * DDIM;
    const float* Tb = T + (size_t)b * SEQ * DDIM;
    const float* pa[2]; const float* pb[2];
    float4 ra[2][2], rb[2][2];
    if (FUSED) {
        #pragma unroll
        for (int i = 0; i < 2; ++i) {
            int g = t + i * 256;
            int m = g >> 6, kg = (g >> 4) & 3, r = g & 15;
            pa[i] = Sb + (size_t)(by * 128 + m * 16 + r) * DDIM + kg * 8;
            pb[i] = Tb + (size_t)(bx * 128 + m * 16 + r) * DDIM + kg * 8;
        }
    }

    auto LOADREGS = [&](int ks) {
        #pragma unroll
        for (int i = 0; i < 2; ++i) {
            ra[i][0] = *(const float4*)(pa[i] + ks * 32);
            ra[i][1] = *(const float4*)(pa[i] + ks * 32 + 4);
            rb[i][0] = *(const float4*)(pb[i] + ks * 32);
            rb[i][1] = *(const float4*)(pb[i] + ks * 32 + 4);
        }
    };
    auto STAGE_FUSED = [&]() {
        #pragma unroll
        for (int i = 0; i < 2; ++i) {
            int g = t + i * 256;
            float xa[8] = {ra[i][0].x, ra[i][0].y, ra[i][0].z, ra[i][0].w,
                           ra[i][1].x, ra[i][1].y, ra[i][1].z, ra[i][1].w};
            float xb[8] = {rb[i][0].x, rb[i][0].y, rb[i][0].z, rb[i][0].w,
                           rb[i][1].x, rb[i][1].y, rb[i][1].z, rb[i][1].w};
            u16x8 ah, al, bh, bl;
            #pragma unroll
            for (int e = 0; e < 8; ++e) {
                u16 h = f2bf(xa[e]); ah[e] = h; al[e] = f2bf(xa[e] - bf2f(h));
                u16 g2 = f2bf(xb[e]); bh[e] = g2; bl[e] = f2bf(xb[e] - bf2f(g2));
            }
            *(u16x8*)&lds[(size_t)g * 8]         = ah;
            *(u16x8*)&lds[4096 + (size_t)g * 8]  = al;
            *(u16x8*)&lds[8192 + (size_t)g * 8]  = bh;
            *(u16x8*)&lds[12288 + (size_t)g * 8] = bl;
        }
    };
    auto STAGE_GLDS = [&](int ks) {
        const u16* sa = Achunk + (size_t)ks * CHUNK_U + (w * 4) * 512 + lane * 8;
        const u16* sb = Bchunk + (size_t)ks * CHUNK_U + (w * 4) * 512 + lane * 8;
        #pragma unroll
        for (int j = 0; j < 4; ++j)
            glds16(sa + j * 512, &lds[(w * 4 + j) * 512]);
        #pragma unroll
        for (int j = 0; j < 4; ++j)
            glds16(sb + j * 512, &lds[8192 + (w * 4 + j) * 512]);
    };
    auto COMPUTE = [&]() {
        const u16* L = &lds[0];
        bf16x8 ah[4], al[4], bh[4], bl[4];
        #pragma unroll
        for (int m = 0; m < 4; ++m) {
            int sm = wr * 4 + m;
            ah[m] = *(const bf16x8*)(L + sm * 512 + lane * 8);
            al[m] = *(const bf16x8*)(L + 4096 + sm * 512 + lane * 8);
        }
        #pragma unroll
        for (int n = 0; n < 4; ++n) {
            int sn = wc * 4 + n;
            bh[n] = *(const bf16x8*)(L + 8192 + sn * 512 + lane * 8);
            bl[n] = *(const bf16x8*)(L + 12288 + sn * 512 + lane * 8);
        }
        #pragma unroll
        for (int m = 0; m < 4; ++m)
            #pragma unroll
            for (int n = 0; n < 4; ++n) {
                acc[m][n] = __builtin_amdgcn_mfma_f32_16x16x32_bf16(ah[m], bh[n], acc[m][n], 0, 0, 0);
                acc[m][n] = __builtin_amdgcn_mfma_f32_16x16x32_bf16(ah[m], bl[n], acc[m][n], 0, 0, 0);
                acc[m][n] = __builtin_amdgcn_mfma_f32_16x16x32_bf16(al[m], bh[n], acc[m][n], 0, 0, 0);
            }
    };

    if (FUSED) {
        LOADREGS(0);
        for (int ks = 0; ks < NKSTEP; ++ks) {
            STAGE_FUSED();
            __syncthreads();
            if (ks + 1 < NKSTEP) LOADREGS(ks + 1);
            COMPUTE();
            __syncthreads();
        }
    } else {
        #pragma unroll 1
        for (int ks = 0; ks < NKSTEP; ++ks) {
            STAGE_GLDS(ks);
            __syncthreads();
            COMPUTE();
            __syncthreads();
        }
    }

    // epilogue: c0 = (1 - cos(dot))/2, store, accumulate sum/sumsq
    float lsum = 0.f, lsq = 0.f;
    float* outb = out + (size_t)b * SEQ * SEQ;
    const int rbase = by * 128 + wr * 64;
    const int cbase = bx * 128 + wc * 64;
    const int cr = lane >> 4;
    const int cc = lane & 15;
    #pragma unroll
    for (int m = 0; m < 4; ++m) {
        #pragma unroll
        for (int n = 0; n < 4; ++n) {
            int col = cbase + n * 16 + cc;
            #pragma unroll
            for (int j = 0; j < 4; ++j) {
                int row = rbase + m * 16 + cr * 4 + j;
                float d  = acc[m][n][j];
                float c0 = 0.5f - 0.5f * __cosf(d);
                outb[(size_t)row * SEQ + col] = c0;
                lsum += c0;
                lsq  = fmaf(c0, c0, lsq);
            }
        }
    }

    double s = (double)lsum, q = (double)lsq;
    #pragma unroll
    for (int o = 32; o; o >>= 1) { s += __shfl_down(s, o); q += __shfl_down(q, o); }
    if (lane == 0) { red[w] = s; red[4 + w] = q; }
    __syncthreads();
    if (t == 0) {
        s = red[0] + red[1] + red[2] + red[3];
        q = red[4] + red[5] + red[6] + red[7];
        atomicAdd(&batch_sums[b * 2 + 0], s);
        atomicAdd(&batch_sums[b * 2 + 1], q);
    }
}

// ---------------- Kernel C: finalize ----------------
__global__ __launch_bounds__(256) void finalize_kernel(
    float* __restrict__ out, const double* __restrict__ batch_sums,
    const float* __restrict__ sproj, const float* __restrict__ tproj,
    const float* __restrict__ cterm_p, const float* __restrict__ alpha_p)
{
    const double n = (double)SEQ * (double)SEQ;
    size_t idx4 = (size_t)blockIdx.x * blockDim.x + threadIdx.x;
    size_t base = idx4 * 4;
    int batch = (int)(base >> 20);
    int rem   = (int)(base & ((SEQ * SEQ) - 1));
    int srow  = rem >> 10;
    int tcol  = rem & (SEQ - 1);

    double sum = batch_sums[batch * 2 + 0];
    double sq  = batch_sums[batch * 2 + 1];
    double var = (sq - sum * sum / n) / (n - 1.0);
    float inv_std = (float)(1.0 / sqrt(var));

    float alpha = *alpha_p;
    float ct    = *cterm_p;
    float sp    = sproj[batch * SEQ + srow];
    float4 tp   = *(const float4*)&tproj[batch * SEQ + tcol];
    float4 c    = *(float4*)&out[base];

    float4 r;
    { float x = c.x * inv_std; float g = __expf(-0.5f * x * x);
      float z = sp + tp.x + ct; float cd = 1.f / (1.f + __expf(-z)); r.x = alpha * (g + cd); }
    { float x = c.y * inv_std; float g = __expf(-0.5f * x * x);
      float z = sp + tp.y + ct; float cd = 1.f / (1.f + __expf(-z)); r.y = alpha * (g + cd); }
    { float x = c.z * inv_std; float g = __expf(-0.5f * x * x);
      float z = sp + tp.z + ct; float cd = 1.f / (1.f + __expf(-z)); r.z = alpha * (g + cd); }
    { float x = c.w * inv_std; float g = __expf(-0.5f * x * x);
      float z = sp + tp.w + ct; float cd = 1.f / (1.f + __expf(-z)); r.w = alpha * (g + cd); }
    *(float4*)&out[base] = r;
}

// ---------------- launch ----------------
extern "C" void kernel_launch(void* const* d_in, const int* in_sizes, int n_in,
                              void* d_out, int out_size, void* d_ws, size_t ws_size,
                              hipStream_t stream) {
    const float* S      = (const float*)d_in[0];
    const float* T      = (const float*)d_in[1];
    const float* W      = (const float*)d_in[2];
    const float* bcost  = (const float*)d_in[3];
    const float* temb   = (const float*)d_in[4];
    const float* alpha  = (const float*)d_in[5];
    const int*   taskid = (const int*)d_in[6];
    float* out = (float*)d_out;

    double* batch_sums = (double*)d_ws;                 // 16 doubles @ 0
    float*  sproj = (float*)((char*)d_ws + 128);        // 8192 floats
    float*  tproj = sproj + BATCHES * SEQ;              // 8192 floats
    float*  cterm = tproj + BATCHES * SEQ;              // 1 float

    const size_t ZERO_BYTES = 128 + sizeof(float) * (2 * BATCHES * SEQ + 1);
    const size_t SMALL = (size_t)1 << 20;
    const size_t CONV_U = (size_t)BATCHES * NPANEL * NKSTEP * CHUNK_U;  // per tensor
    const size_t NEEDED = SMALL + 2 * CONV_U * sizeof(u16);
    u16* Sg = (u16*)((char*)d_ws + SMALL);
    u16* Tg = Sg + CONV_U;

    hipMemsetAsync(d_ws, 0, ZERO_BYTES, stream);

    if (ws_size >= NEEDED) {
        prep_kernel<<<(2 * BATCHES * NPANEL * NKSTEP * 512) / 256, 256, 0, stream>>>(
            S, T, W, bcost, temb, taskid, Sg, Tg, sproj, tproj, cterm);
        gemm_kernel<false><<<512, 256, 0, stream>>>(S, T, Sg, Tg, out, batch_sums);
    } else {
        proj_kernel<<<4097, 256, 0, stream>>>(S, T, W, bcost, temb, taskid,
                                              sproj, tproj, cterm);
        gemm_kernel<true><<<512, 256, 0, stream>>>(S, T, Sg, Tg, out, batch_sums);
    }

    int nblk = (BATCHES * SEQ * SEQ) / (256 * 4);
    finalize_kernel<<<nblk, 256, 0, stream>>>(out, batch_sums, sproj, tproj,
                                              cterm, alpha);
}